// Round 8
// baseline (475.928 us; speedup 1.0000x reference)
//
#include <hip/hip_runtime.h>
#include <math.h>

#define D 128
#define H 8
#define HD 16

typedef __attribute__((ext_vector_type(8))) short bf16x8;
typedef __attribute__((ext_vector_type(4))) float f32x4;

__device__ __forceinline__ ushort f2bf(float x) {
    union { float f; unsigned u; } v; v.f = x;
    unsigned r = v.u + 0x7fffu + ((v.u >> 16) & 1u);   // RNE
    return (ushort)(r >> 16);
}
__device__ __forceinline__ float bflo(unsigned u) {
    union { unsigned u; float f; } x; x.u = u << 16; return x.f;
}
__device__ __forceinline__ float bfhi(unsigned u) {
    union { unsigned u; float f; } x; x.u = u & 0xffff0000u; return x.f;
}
__device__ __forceinline__ float bf2f(short s) {
    union { unsigned u; float f; } x; x.u = ((unsigned)(ushort)s) << 16; return x.f;
}

__device__ __forceinline__ float dot16(const float* qf, uint4 a, uint4 b) {
    float w;
    w  = qf[0]  * bflo(a.x) + qf[1]  * bfhi(a.x);
    w += qf[2]  * bflo(a.y) + qf[3]  * bfhi(a.y);
    w += qf[4]  * bflo(a.z) + qf[5]  * bfhi(a.z);
    w += qf[6]  * bflo(a.w) + qf[7]  * bfhi(a.w);
    w += qf[8]  * bflo(b.x) + qf[9]  * bfhi(b.x);
    w += qf[10] * bflo(b.y) + qf[11] * bfhi(b.y);
    w += qf[12] * bflo(b.z) + qf[13] * bfhi(b.z);
    w += qf[14] * bflo(b.w) + qf[15] * bfhi(b.w);
    return w;
}
__device__ __forceinline__ void acc16(float* num, float e, uint4 a, uint4 b) {
    num[0]  = fmaf(e, bflo(a.x), num[0]);  num[1]  = fmaf(e, bfhi(a.x), num[1]);
    num[2]  = fmaf(e, bflo(a.y), num[2]);  num[3]  = fmaf(e, bfhi(a.y), num[3]);
    num[4]  = fmaf(e, bflo(a.z), num[4]);  num[5]  = fmaf(e, bfhi(a.z), num[5]);
    num[6]  = fmaf(e, bflo(a.w), num[6]);  num[7]  = fmaf(e, bfhi(a.w), num[7]);
    num[8]  = fmaf(e, bflo(b.x), num[8]);  num[9]  = fmaf(e, bfhi(b.x), num[9]);
    num[10] = fmaf(e, bflo(b.y), num[10]); num[11] = fmaf(e, bfhi(b.y), num[11]);
    num[12] = fmaf(e, bflo(b.z), num[12]); num[13] = fmaf(e, bfhi(b.z), num[13]);
    num[14] = fmaf(e, bflo(b.w), num[14]); num[15] = fmaf(e, bfhi(b.w), num[15]);
}

// ---------------------------------------------------------------------------
// GEMM v3: 32 rows/block, 4 waves x 32 cols = 128 cols/block via blockIdx.y.
// B (weights) staged cooperatively into LDS with XOR swizzle so the K-loop's
// ds_read_b128 is conflict-free (16B unit u stored at u^(col&7); lanes lr=0..7
// then hit 8 distinct 16B slots = all 32 banks; lr 8..15 duplicate = free
// 2-way). A kept in registers (2 strips/wave), loads issued before the
// staging barrier to overlap. R6 lessons applied: prologue-only barrier,
// no threadfence, no ticket.
// AMODE: 0 = A bf16; 1 = A fp32 (convert); 2 = A bf16 + BN from RAW stats
//        (scale/shift computed in-block into LDS from sums + g/b).
// EPI:   0 = bias; 2 = bias+leaky; 3 = bias + fp32 residual (extra);
//        4 = bias + BN1(bf16 extra) residual, BN from raw stats. Out bf16.
// ---------------------------------------------------------------------------
template<int AMODE, int EPI, int K, int M>
__global__ __launch_bounds__(256)
void gemm_v3_kernel(const void* __restrict__ Ap,
                    const ushort* __restrict__ W,
                    const float* __restrict__ bias,
                    const void* __restrict__ extra,
                    const float* __restrict__ rawstats,
                    const float* __restrict__ gg,
                    const float* __restrict__ bb,
                    ushort* __restrict__ outb,
                    int N)
{
    constexpr int KC  = (K < 128) ? K : 128;
    constexpr int KT  = KC / 32;       // 4
    constexpr int NKC = K / KC;

    __shared__ ushort Bs[128 * 128];   // 32 KB: 128 cols x 256B (swizzled)
    __shared__ float scs[128], shs[128];

    const int tid = threadIdx.x;
    const int lane = tid & 63, wave = tid >> 6;
    const int lr = lane & 15, lq = lane >> 4;
    const int row0 = blockIdx.x * 32;
    const int colbase = blockIdx.y * 128;

    int ar0 = min(row0 + lr, N - 1);
    int ar1 = min(row0 + 16 + lr, N - 1);

    // BN scale/shift precompute from raw sums (AMODE==2 consumers)
    if (AMODE == 2 && tid < 128) {
        float mean = rawstats[tid] / (float)N;
        float var  = rawstats[128 + tid] / (float)N - mean * mean;
        float sc = gg[tid] * rsqrtf(var + 1e-5f);
        scs[tid] = sc;
        shs[tid] = bb[tid] - mean * sc;
    }

    bf16x8 afr[2][KT];
    bf16x8 araw[2][KT];

    auto loadAraw = [&](int kc) {
        #pragma unroll
        for (int s = 0; s < 2; ++s) {
            int ar = s ? ar1 : ar0;
            if (AMODE == 1) {
                const float* ap = (const float*)Ap + (size_t)ar * K + lq * 8;
                #pragma unroll
                for (int t = 0; t < KT; ++t) {
                    float4 f0 = *(const float4*)(ap + t * 32);
                    float4 f1 = *(const float4*)(ap + t * 32 + 4);
                    bf16x8 o;
                    o[0] = (short)f2bf(f0.x); o[1] = (short)f2bf(f0.y);
                    o[2] = (short)f2bf(f0.z); o[3] = (short)f2bf(f0.w);
                    o[4] = (short)f2bf(f1.x); o[5] = (short)f2bf(f1.y);
                    o[6] = (short)f2bf(f1.z); o[7] = (short)f2bf(f1.w);
                    afr[s][t] = o;
                }
            } else {
                const ushort* ap = (const ushort*)Ap + (size_t)ar * K + kc * KC + lq * 8;
                #pragma unroll
                for (int t = 0; t < KT; ++t) {
                    bf16x8 raw = *(const bf16x8*)(ap + t * 32);
                    if (AMODE == 0) afr[s][t] = raw;
                    else            araw[s][t] = raw;
                }
            }
        }
    };

    // cooperative B staging: chunk kc -> Bs (swizzled), perfectly coalesced
    auto stageB = [&](int kc) {
        #pragma unroll
        for (int it = 0; it < 8; ++it) {
            int idx = tid + it * 256;        // 16B chunk index, 0..2047
            int c = idx >> 4, u = idx & 15;
            const uint4* gp = (const uint4*)(W + (size_t)(colbase + c) * K + kc * KC) + u;
            *(uint4*)&Bs[c * 128 + 8 * (u ^ (c & 7))] = *gp;
        }
    };

    const float*  extf = (const float*)extra;
    const ushort* extb = (const ushort*)extra;

    f32x4 acc[2][2] = {};

    #pragma unroll 1
    for (int kc = 0; kc < NKC; ++kc) {
        loadAraw(kc);                         // issue global A loads early
        if (kc > 0) __syncthreads();          // protect LDS reuse
        stageB(kc);
        __syncthreads();

        if (AMODE == 2) {
            #pragma unroll
            for (int s = 0; s < 2; ++s)
                #pragma unroll
                for (int t = 0; t < KT; ++t) {
                    bf16x8 raw = araw[s][t];
                    int kb = t * 32 + lq * 8;
                    bf16x8 o;
                    #pragma unroll
                    for (int e = 0; e < 8; ++e)
                        o[e] = (short)f2bf(fmaf(bf2f(raw[e]), scs[kb + e], shs[kb + e]));
                    afr[s][t] = o;
                }
        }

        const int cl0 = wave * 32 + lr;       // ct=0 col (local)
        const int cl1 = cl0 + 16;             // ct=1 col (local)
        #pragma unroll
        for (int t = 0; t < KT; ++t) {
            int u = t * 4 + lq;
            bf16x8 b0 = *(const bf16x8*)&Bs[cl0 * 128 + 8 * (u ^ (cl0 & 7))];
            bf16x8 b1 = *(const bf16x8*)&Bs[cl1 * 128 + 8 * (u ^ (cl1 & 7))];
            acc[0][0] = __builtin_amdgcn_mfma_f32_16x16x32_bf16(afr[0][t], b0, acc[0][0], 0, 0, 0);
            acc[1][0] = __builtin_amdgcn_mfma_f32_16x16x32_bf16(afr[1][t], b0, acc[1][0], 0, 0, 0);
            acc[0][1] = __builtin_amdgcn_mfma_f32_16x16x32_bf16(afr[0][t], b1, acc[0][1], 0, 0, 0);
            acc[1][1] = __builtin_amdgcn_mfma_f32_16x16x32_bf16(afr[1][t], b1, acc[1][1], 0, 0, 0);
        }
    }

    #pragma unroll
    for (int ct = 0; ct < 2; ++ct) {
        int gcol = colbase + wave * 32 + ct * 16 + lr;
        float biasv = bias[gcol];
        float scv = 0.f, shv = 0.f;
        if (EPI == 4) {   // BN1 residual scale/shift from raw stats (2 cols/lane)
            float mean = rawstats[gcol] / (float)N;
            float var  = rawstats[128 + gcol] / (float)N - mean * mean;
            scv = gg[gcol] * rsqrtf(var + 1e-5f);
            shv = bb[gcol] - mean * scv;
        }
        #pragma unroll
        for (int s = 0; s < 2; ++s) {
            #pragma unroll
            for (int r = 0; r < 4; ++r) {
                int grow = row0 + s * 16 + lq * 4 + r;
                if (grow >= N) continue;
                size_t o = (size_t)grow * M + gcol;
                float v = acc[s][ct][r] + biasv;
                if (EPI == 2)      v = v > 0.f ? v : 0.01f * v;
                else if (EPI == 3) v += extf[o];
                else if (EPI == 4) v += fmaf(bf2f((short)extb[o]), scv, shv);
                outb[o] = f2bf(v);
            }
        }
    }
}

// ---------------------------------------------------------------------------
// Merged: weight conversion (i < cw_total) + edge degree count (i < E0).
// QKV fused [384x128] with q-scaling folded; bqkv = {0.25*q_b, 0, 0}.
// ---------------------------------------------------------------------------
__global__ __launch_bounds__(256)
void convert_deg_kernel(const float* __restrict__ qw, const float* __restrict__ qb,
                        const float* __restrict__ kw, const float* __restrict__ vw,
                        const float* __restrict__ ow, const float* __restrict__ w1,
                        const float* __restrict__ w2,
                        ushort* __restrict__ wqkv, ushort* __restrict__ wout,
                        ushort* __restrict__ w1b, ushort* __restrict__ w2b,
                        float* __restrict__ bqkv,
                        const int* __restrict__ ei, long long E0,
                        int* __restrict__ deg)
{
    long long i = (long long)blockIdx.x * 256 + threadIdx.x;
    if (i < E0) atomicAdd(&deg[ei[E0 + i]], 1);
    if (i < 49152) {
        int row = (int)i >> 7;
        float v;
        if (row < 128)      v = 0.25f * qw[i];
        else if (row < 256) v = kw[i - 16384];
        else                v = vw[i - 32768];
        wqkv[i] = f2bf(v);
        return;
    }
    long long j = i - 49152;
    if (j < 16384) { wout[j] = f2bf(ow[j]); return; }
    j -= 16384;
    if (j < 65536) { w1b[j] = f2bf(w1[j]); return; }
    j -= 65536;
    if (j < 65536) { w2b[j] = f2bf(w2[j]); return; }
    j -= 65536;
    if (j < 384) bqkv[j] = (j < 128) ? 0.25f * qb[j] : 0.f;
}

// ---------------------------------------------------------------------------
// CSR build scans + scatter.
// ---------------------------------------------------------------------------
__global__ __launch_bounds__(256)
void scan_block_sum(const int* __restrict__ deg, int n, int* __restrict__ bsum)
{
    __shared__ int sh[256];
    int i = blockIdx.x * 256 + threadIdx.x;
    sh[threadIdx.x] = (i < n) ? deg[i] : 0;
    __syncthreads();
    for (int ofs = 128; ofs > 0; ofs >>= 1) {
        if (threadIdx.x < ofs) sh[threadIdx.x] += sh[threadIdx.x + ofs];
        __syncthreads();
    }
    if (threadIdx.x == 0) bsum[blockIdx.x] = sh[0];
}

__global__ __launch_bounds__(256)
void scan_final(const int* __restrict__ deg, int n, const int* __restrict__ bsum,
                int nb, int* __restrict__ rowptr)
{
    __shared__ int sb[256];
    __shared__ int sh[256];
    int t = threadIdx.x;
    sb[t] = (t < nb) ? bsum[t] : 0;
    __syncthreads();
    for (int ofs = 1; ofs < 256; ofs <<= 1) {
        int v = (t >= ofs) ? sb[t - ofs] : 0;
        __syncthreads();
        sb[t] += v;
        __syncthreads();
    }
    int boff = (blockIdx.x == 0) ? 0 : sb[blockIdx.x - 1];

    int i = blockIdx.x * 256 + t;
    int v = (i < n) ? deg[i] : 0;
    sh[t] = v;
    __syncthreads();
    for (int ofs = 1; ofs < 256; ofs <<= 1) {
        int u = (t >= ofs) ? sh[t - ofs] : 0;
        __syncthreads();
        sh[t] += u;
        __syncthreads();
    }
    if (i < n) rowptr[i] = boff + sh[t] - v;
    if (i == n - 1) rowptr[n] = boff + sh[t];
}

__global__ __launch_bounds__(256)
void scatter_kernel(const int* __restrict__ ei, long long E0,
                    const int* __restrict__ rowptr, int* __restrict__ cnt,
                    int* __restrict__ col)
{
    long long e = (long long)blockIdx.x * 256 + threadIdx.x;
    if (e >= E0) return;
    int s = ei[e], d = ei[E0 + e];
    int pos = rowptr[d] + atomicAdd(&cnt[d], 1);
    col[pos] = s;
}

// ---------------------------------------------------------------------------
// Fused gather attention, WAVE-PER-NODE (R7-proven): 64 lanes = 8 heads x 8
// edge slots, butterfly reduce. qkv row = 48 uint4: q h*2, k 16+h*2, v 32+h*2.
// ---------------------------------------------------------------------------
__global__ __launch_bounds__(256)
void gat_agg_kernel(const int* __restrict__ rowptr, const int* __restrict__ col,
                    const ushort* __restrict__ qkv, ushort* __restrict__ agg, int N)
{
    int node = blockIdx.x * 4 + (threadIdx.x >> 6);
    if (node >= N) return;
    int lane = threadIdx.x & 63;
    int es = lane >> 3, h = lane & 7;
    const uint4* Q = (const uint4*)qkv;

    const uint4* qp = Q + (size_t)node * 48 + h * 2;
    uint4 qa = qp[0], qb = qp[1];
    float qf[16];
    qf[0]=bflo(qa.x); qf[1]=bfhi(qa.x); qf[2]=bflo(qa.y); qf[3]=bfhi(qa.y);
    qf[4]=bflo(qa.z); qf[5]=bfhi(qa.z); qf[6]=bflo(qa.w); qf[7]=bfhi(qa.w);
    qf[8]=bflo(qb.x); qf[9]=bfhi(qb.x); qf[10]=bflo(qb.y); qf[11]=bfhi(qb.y);
    qf[12]=bflo(qb.z); qf[13]=bfhi(qb.z); qf[14]=bflo(qb.w); qf[15]=bfhi(qb.w);

    float num[16];
    #pragma unroll
    for (int i = 0; i < 16; i++) num[i] = 0.f;
    float den = 0.f;

    int beg = rowptr[node];
    int total = rowptr[node + 1] - beg + 1;   // + self loop at idx 0
    for (int idx = es; idx < total; idx += 8) {
        int s = (idx == 0) ? node : col[beg + idx - 1];
        const uint4* rp = Q + (size_t)s * 48 + h * 2;
        uint4 ka = rp[16], kb = rp[17], va = rp[32], vb = rp[33];
        float ev = __expf(dot16(qf, ka, kb));
        den += ev;
        acc16(num, ev, va, vb);
    }

    #pragma unroll
    for (int m = 8; m < 64; m <<= 1) {
        den += __shfl_xor(den, m, 64);
        #pragma unroll
        for (int i = 0; i < 16; i++) num[i] += __shfl_xor(num[i], m, 64);
    }

    if (es == 0) {
        float inv = 1.f / (den + 1e-16f);
        uint4 o0, o1;
        o0.x = (uint)f2bf(num[0]*inv)  | ((uint)f2bf(num[1]*inv)  << 16);
        o0.y = (uint)f2bf(num[2]*inv)  | ((uint)f2bf(num[3]*inv)  << 16);
        o0.z = (uint)f2bf(num[4]*inv)  | ((uint)f2bf(num[5]*inv)  << 16);
        o0.w = (uint)f2bf(num[6]*inv)  | ((uint)f2bf(num[7]*inv)  << 16);
        o1.x = (uint)f2bf(num[8]*inv)  | ((uint)f2bf(num[9]*inv)  << 16);
        o1.y = (uint)f2bf(num[10]*inv) | ((uint)f2bf(num[11]*inv) << 16);
        o1.z = (uint)f2bf(num[12]*inv) | ((uint)f2bf(num[13]*inv) << 16);
        o1.w = (uint)f2bf(num[14]*inv) | ((uint)f2bf(num[15]*inv) << 16);
        uint4* op = (uint4*)(agg + (size_t)node * 128 + h * 16);
        op[0] = o0; op[1] = o1;
    }
}

// ---------------------------------------------------------------------------
// BatchNorm raw stats over a bf16 [N x 128] tensor (sum, sumsq atomics).
// ---------------------------------------------------------------------------
__global__ __launch_bounds__(256)
void bn_stats_bf16_kernel(const ushort* __restrict__ y, int N, float* __restrict__ stats)
{
    int jp = threadIdx.x & 63;
    int q4 = threadIdx.x >> 6;
    int r = blockIdx.x * 256 + q4;
    int rend = min(N, (int)(blockIdx.x + 1) * 256);
    float s0 = 0.f, qq0 = 0.f, s1 = 0.f, qq1 = 0.f;
    const uint* yp = (const uint*)y;
    for (; r < rend; r += 4) {
        uint u = yp[(size_t)r * 64 + jp];
        float a = bflo(u), b = bfhi(u);
        s0 += a; qq0 += a * a; s1 += b; qq1 += b * b;
    }
    __shared__ float sh[4][64][4];
    sh[q4][jp][0] = s0; sh[q4][jp][1] = qq0; sh[q4][jp][2] = s1; sh[q4][jp][3] = qq1;
    __syncthreads();
    if (threadIdx.x < 128) {
        int p = threadIdx.x >> 1;
        int w = threadIdx.x & 1;
        float ss = 0.f, sq = 0.f;
        #pragma unroll
        for (int i = 0; i < 4; i++) { ss += sh[i][p][w * 2]; sq += sh[i][p][w * 2 + 1]; }
        unsafeAtomicAdd(&stats[2 * p + w], ss);
        unsafeAtomicAdd(&stats[128 + 2 * p + w], sq);
    }
}

// final BN apply (finalize folded in from raw stats): bf16 in -> fp32 out
__global__ __launch_bounds__(256)
void bn_apply_out_kernel(const ushort* __restrict__ y, const float* __restrict__ rawstats,
                         const float* __restrict__ g, const float* __restrict__ b,
                         float* __restrict__ out, int total4, int N)
{
    __shared__ float scs[128], shs[128];
    if (threadIdx.x < 128) {
        int j = threadIdx.x;
        float mean = rawstats[j] / (float)N;
        float var  = rawstats[128 + j] / (float)N - mean * mean;
        float sc = g[j] * rsqrtf(var + 1e-5f);
        scs[j] = sc;
        shs[j] = b[j] - mean * sc;
    }
    __syncthreads();
    int i = blockIdx.x * 256 + threadIdx.x;
    if (i >= total4) return;
    uint2 u = reinterpret_cast<const uint2*>(y)[i];
    int j = (i * 4) & (D - 1);
    float4 v;
    v.x = bflo(u.x) * scs[j + 0] + shs[j + 0];
    v.y = bfhi(u.x) * scs[j + 1] + shs[j + 1];
    v.z = bflo(u.y) * scs[j + 2] + shs[j + 2];
    v.w = bfhi(u.y) * scs[j + 3] + shs[j + 3];
    reinterpret_cast<float4*>(out)[i] = v;
}

// ---------------------------------------------------------------------------
extern "C" void kernel_launch(void* const* d_in, const int* in_sizes, int n_in,
                              void* d_out, int out_size, void* d_ws, size_t ws_size,
                              hipStream_t stream)
{
    const float* src    = (const float*)d_in[0];
    const int*   ei     = (const int*)  d_in[1];
    const float* q_w    = (const float*)d_in[2];
    const float* q_b    = (const float*)d_in[3];
    const float* k_w    = (const float*)d_in[4];
    const float* v_w    = (const float*)d_in[5];
    const float* out_w  = (const float*)d_in[6];
    const float* out_b  = (const float*)d_in[7];
    const float* g1     = (const float*)d_in[8];
    const float* b1     = (const float*)d_in[9];
    const float* lin1_w = (const float*)d_in[10];
    const float* lin1_b = (const float*)d_in[11];
    const float* lin2_w = (const float*)d_in[12];
    const float* lin2_b = (const float*)d_in[13];
    const float* g2     = (const float*)d_in[14];
    const float* b2     = (const float*)d_in[15];

    const int N        = in_sizes[0] / D;        // 50000
    const long long E0 = in_sizes[1] / 2;        // 800000

    // ---- workspace layout (float units) ----
    float* ws = (float*)d_ws;
    size_t off = 0;
    ushort* qkv  = (ushort*)(ws + off); off += (size_t)N * 192;   // N*384 bf16
    ushort* agg  = (ushort*)(ws + off); off += (size_t)N * 64;
    ushort* y1b  = (ushort*)(ws + off); off += (size_t)N * 64;
    ushort* hid  = (ushort*)(ws + off); off += (size_t)N * 256;   // N*512 bf16
    ushort* y2b  = (ushort*)(ws + off); off += (size_t)N * 64;
    ushort* wqkv = (ushort*)(ws + off); off += 24576;             // 384*128
    ushort* woutb= (ushort*)(ws + off); off += 8192;              // 128*128
    ushort* w1b  = (ushort*)(ws + off); off += 32768;             // 512*128
    ushort* w2b  = (ushort*)(ws + off); off += 32768;             // 128*512
    float*  bqkv = ws + off;            off += 384;
    size_t zero_start = off;
    int* deg    = (int*)(ws + off); off += N;
    int* cnt    = (int*)(ws + off); off += N;
    float* stats1 = ws + off; off += 512;
    float* stats2 = ws + off; off += 512;
    size_t zero_cnt = off - zero_start;
    int* rowptr = (int*)(ws + off); off += N + 1;
    int* bsum   = (int*)(ws + off); off += 256;
    int* col    = (int*)(ws + off); off += E0;

    hipMemsetAsync(ws + zero_start, 0, zero_cnt * sizeof(float), stream);

    dim3 blk(256);

    // ---- merged weight conversion + degree count ----
    dim3 gE0((unsigned)((E0 + 255) / 256));
    hipLaunchKernelGGL(convert_deg_kernel, gE0, blk, 0, stream,
                       q_w, q_b, k_w, v_w, out_w, lin1_w, lin2_w,
                       wqkv, woutb, w1b, w2b, bqkv, ei, E0, deg);

    // ---- CSR scans + scatter ----
    int nb = (N + 255) / 256;   // 196
    hipLaunchKernelGGL(scan_block_sum, dim3(nb), blk, 0, stream, deg, N, bsum);
    hipLaunchKernelGGL(scan_final, dim3(nb), blk, 0, stream, deg, N, bsum, nb, rowptr);
    hipLaunchKernelGGL(scatter_kernel, gE0, blk, 0, stream, ei, E0, rowptr, cnt, col);

    int gx = (N + 31) / 32;   // 1563

    // ---- fused QKV projection (A fp32, converted on load), M=384 ----
    hipLaunchKernelGGL((gemm_v3_kernel<1, 0, 128, 384>), dim3(gx, 3), blk, 0, stream,
                       src, wqkv, bqkv, nullptr, nullptr, nullptr, nullptr, qkv, N);

    // ---- fused softmax + aggregation (wave per node) ----
    hipLaunchKernelGGL(gat_agg_kernel, dim3((N + 3) / 4), blk, 0, stream,
                       rowptr, col, qkv, agg, N);

    // ---- out-projection + bias + fp32 src residual -> y1 bf16 ----
    hipLaunchKernelGGL((gemm_v3_kernel<0, 3, 128, 128>), dim3(gx, 1), blk, 0, stream,
                       agg, woutb, out_b, src, nullptr, nullptr, nullptr, y1b, N);

    // ---- BN1 raw stats ----
    dim3 gS((N + 255) / 256);
    hipLaunchKernelGGL(bn_stats_bf16_kernel, gS, blk, 0, stream, y1b, N, stats1);

    // ---- lin1: BN1 on A-load (from raw stats), leaky -> hid bf16, M=512 ----
    hipLaunchKernelGGL((gemm_v3_kernel<2, 2, 128, 512>), dim3(gx, 4), blk, 0, stream,
                       y1b, w1b, lin1_b, nullptr, stats1, g1, b1, hid, N);

    // ---- lin2 + bias + BN1(y1) residual (raw stats) -> y2 bf16, K=512 ----
    hipLaunchKernelGGL((gemm_v3_kernel<0, 4, 512, 128>), dim3(gx, 1), blk, 0, stream,
                       hid, w2b, lin2_b, y1b, stats1, g1, b1, y2b, N);

    // ---- BN2 raw stats + apply (finalize folded) -> d_out fp32 ----
    hipLaunchKernelGGL(bn_stats_bf16_kernel, gS, blk, 0, stream, y2b, N, stats2);
    int total4 = N * D / 4;
    hipLaunchKernelGGL(bn_apply_out_kernel, dim3((total4 + 255) / 256), blk, 0, stream,
                       y2b, stats2, g2, b2, (float*)d_out, total4, N);
}

// Round 9
// 447.473 us; speedup vs baseline: 1.0636x; 1.0636x over previous
//
#include <hip/hip_runtime.h>
#include <math.h>

#define D 128
#define H 8
#define HD 16

typedef __attribute__((ext_vector_type(8))) short bf16x8;
typedef __attribute__((ext_vector_type(4))) float f32x4;

__device__ __forceinline__ ushort f2bf(float x) {
    union { float f; unsigned u; } v; v.f = x;
    unsigned r = v.u + 0x7fffu + ((v.u >> 16) & 1u);   // RNE
    return (ushort)(r >> 16);
}
__device__ __forceinline__ float bflo(unsigned u) {
    union { unsigned u; float f; } x; x.u = u << 16; return x.f;
}
__device__ __forceinline__ float bfhi(unsigned u) {
    union { unsigned u; float f; } x; x.u = u & 0xffff0000u; return x.f;
}
__device__ __forceinline__ float bf2f(short s) {
    union { unsigned u; float f; } x; x.u = ((unsigned)(ushort)s) << 16; return x.f;
}

__device__ __forceinline__ float dot16(const float* qf, uint4 a, uint4 b) {
    float w;
    w  = qf[0]  * bflo(a.x) + qf[1]  * bfhi(a.x);
    w += qf[2]  * bflo(a.y) + qf[3]  * bfhi(a.y);
    w += qf[4]  * bflo(a.z) + qf[5]  * bfhi(a.z);
    w += qf[6]  * bflo(a.w) + qf[7]  * bfhi(a.w);
    w += qf[8]  * bflo(b.x) + qf[9]  * bfhi(b.x);
    w += qf[10] * bflo(b.y) + qf[11] * bfhi(b.y);
    w += qf[12] * bflo(b.z) + qf[13] * bfhi(b.z);
    w += qf[14] * bflo(b.w) + qf[15] * bfhi(b.w);
    return w;
}
__device__ __forceinline__ void acc16(float* num, float e, uint4 a, uint4 b) {
    num[0]  = fmaf(e, bflo(a.x), num[0]);  num[1]  = fmaf(e, bfhi(a.x), num[1]);
    num[2]  = fmaf(e, bflo(a.y), num[2]);  num[3]  = fmaf(e, bfhi(a.y), num[3]);
    num[4]  = fmaf(e, bflo(a.z), num[4]);  num[5]  = fmaf(e, bfhi(a.z), num[5]);
    num[6]  = fmaf(e, bflo(a.w), num[6]);  num[7]  = fmaf(e, bfhi(a.w), num[7]);
    num[8]  = fmaf(e, bflo(b.x), num[8]);  num[9]  = fmaf(e, bfhi(b.x), num[9]);
    num[10] = fmaf(e, bflo(b.y), num[10]); num[11] = fmaf(e, bfhi(b.y), num[11]);
    num[12] = fmaf(e, bflo(b.z), num[12]); num[13] = fmaf(e, bfhi(b.z), num[13]);
    num[14] = fmaf(e, bflo(b.w), num[14]); num[15] = fmaf(e, bfhi(b.w), num[15]);
}

// ---------------------------------------------------------------------------
// GEMM v4: B-STATIONARY streaming. K=128 fixed. Block = 4 waves; wave w owns
// cols [blockIdx.y*128 + w*32, +32) and keeps ALL its B-fragments in VGPRs
// (8 bf16x8 = 32 regs, loaded once — weights are L2-hot). Grid-strides over
// 32-row A chunks, prefetching the next chunk's A-frags during MFMA+store.
// No LDS, no barriers (R6/R8 lesson: block-local B staging loses).
// EPI: 0 = bias -> bf16; 2 = bias+leaky -> bf16; 3 = bias + fp32 residual.
// ---------------------------------------------------------------------------
template<int EPI, int M>
__global__ __launch_bounds__(256)
void gemm_v4_kernel(const ushort* __restrict__ A,
                    const ushort* __restrict__ W,
                    const float* __restrict__ bias,
                    const float* __restrict__ extf,
                    ushort* __restrict__ outb, int N)
{
    const int lane = threadIdx.x & 63, wave = threadIdx.x >> 6;
    const int lr = lane & 15, lq = lane >> 4;
    const int colbase = blockIdx.y * 128 + wave * 32;

    // resident B: 2 col-groups x 4 k-tiles
    bf16x8 bfr[2][4];
    {
        const ushort* wp = W + (size_t)(colbase + lr) * 128 + lq * 8;
        #pragma unroll
        for (int ct = 0; ct < 2; ++ct)
            #pragma unroll
            for (int t = 0; t < 4; ++t)
                bfr[ct][t] = *(const bf16x8*)(wp + (size_t)ct * 16 * 128 + t * 32);
    }
    float biasv[2];
    biasv[0] = bias[colbase + lr];
    biasv[1] = bias[colbase + 16 + lr];

    const int stride = gridDim.x * 32;
    int r0 = blockIdx.x * 32;
    if (r0 >= N) return;

    bf16x8 cur[2][4], nxt[2][4];
    auto loadA = [&](int rb, bf16x8 (&dst)[2][4]) {
        #pragma unroll
        for (int s = 0; s < 2; ++s) {
            int ar = min(rb + s * 16 + lr, N - 1);
            const ushort* ap = A + (size_t)ar * 128 + lq * 8;
            #pragma unroll
            for (int t = 0; t < 4; ++t)
                dst[s][t] = *(const bf16x8*)(ap + t * 32);
        }
    };
    loadA(r0, cur);

    while (true) {
        int rn = r0 + stride;
        if (rn < N) loadA(rn, nxt);     // overlap with MFMA + epilogue below

        f32x4 acc[2][2] = {};
        #pragma unroll
        for (int t = 0; t < 4; ++t) {
            acc[0][0] = __builtin_amdgcn_mfma_f32_16x16x32_bf16(cur[0][t], bfr[0][t], acc[0][0], 0, 0, 0);
            acc[1][0] = __builtin_amdgcn_mfma_f32_16x16x32_bf16(cur[1][t], bfr[0][t], acc[1][0], 0, 0, 0);
            acc[0][1] = __builtin_amdgcn_mfma_f32_16x16x32_bf16(cur[0][t], bfr[1][t], acc[0][1], 0, 0, 0);
            acc[1][1] = __builtin_amdgcn_mfma_f32_16x16x32_bf16(cur[1][t], bfr[1][t], acc[1][1], 0, 0, 0);
        }

        #pragma unroll
        for (int ct = 0; ct < 2; ++ct) {
            int gcol = colbase + ct * 16 + lr;
            #pragma unroll
            for (int s = 0; s < 2; ++s) {
                #pragma unroll
                for (int r = 0; r < 4; ++r) {
                    int grow = r0 + s * 16 + lq * 4 + r;
                    if (grow >= N) continue;
                    size_t o = (size_t)grow * M + gcol;
                    float v = acc[s][ct][r] + biasv[ct];
                    if (EPI == 2)      v = v > 0.f ? v : 0.01f * v;
                    else if (EPI == 3) v += extf[o];
                    outb[o] = f2bf(v);
                }
            }
        }

        if (rn >= N) break;
        r0 = rn;
        #pragma unroll
        for (int s = 0; s < 2; ++s)
            #pragma unroll
            for (int t = 0; t < 4; ++t) cur[s][t] = nxt[s][t];
    }
}

// ---------------------------------------------------------------------------
// GEMM v2 (R5/R7-proven) for lin2 only: K=512 A-resident in chunks, B direct
// from global, MW=32. EPI4: bias + BN1(bf16 residual) with scale/shift
// computed from RAW stats1 sums (finalize folded in).
// ---------------------------------------------------------------------------
template<int K, int MW>
__global__ __launch_bounds__(256)
void gemm_v2_kernel(const ushort* __restrict__ Ap,
                    const ushort* __restrict__ W,
                    const float* __restrict__ bias,
                    const ushort* __restrict__ extb,
                    const float* __restrict__ rawstats,
                    const float* __restrict__ gg,
                    const float* __restrict__ bb,
                    ushort* __restrict__ outb,
                    int N)
{
    constexpr int M   = MW * 4;
    constexpr int KC  = 128;
    constexpr int KT  = KC / 32;
    constexpr int NKC = K / KC;

    const int lane = threadIdx.x & 63, wave = threadIdx.x >> 6;
    const int lr = lane & 15, lq = lane >> 4;
    const int row0 = blockIdx.x * 32;
    const int c0w  = wave * MW;

    int ar0 = min(row0 + lr, N - 1);
    int ar1 = min(row0 + 16 + lr, N - 1);

    bf16x8 afr[2][KT];
    auto loadA = [&](int kc) {
        #pragma unroll
        for (int s = 0; s < 2; ++s) {
            int ar = s ? ar1 : ar0;
            const ushort* ap = Ap + (size_t)ar * K + kc * KC + lq * 8;
            #pragma unroll
            for (int t = 0; t < KT; ++t) afr[s][t] = *(const bf16x8*)(ap + t * 32);
        }
    };

    f32x4 acc[2][2] = {};
    #pragma unroll 1
    for (int kc = 0; kc < NKC; ++kc) {
        loadA(kc);
        const ushort* wp0 = W + (size_t)(c0w + lr) * K + kc * KC + lq * 8;
        const ushort* wp1 = wp0 + (size_t)16 * K;
        #pragma unroll
        for (int t = 0; t < KT; ++t) {
            bf16x8 b0 = *(const bf16x8*)(wp0 + t * 32);
            bf16x8 b1 = *(const bf16x8*)(wp1 + t * 32);
            acc[0][0] = __builtin_amdgcn_mfma_f32_16x16x32_bf16(afr[0][t], b0, acc[0][0], 0, 0, 0);
            acc[1][0] = __builtin_amdgcn_mfma_f32_16x16x32_bf16(afr[1][t], b0, acc[1][0], 0, 0, 0);
            acc[0][1] = __builtin_amdgcn_mfma_f32_16x16x32_bf16(afr[0][t], b1, acc[0][1], 0, 0, 0);
            acc[1][1] = __builtin_amdgcn_mfma_f32_16x16x32_bf16(afr[1][t], b1, acc[1][1], 0, 0, 0);
        }
    }

    #pragma unroll
    for (int ct = 0; ct < 2; ++ct) {
        int col = c0w + ct * 16 + lr;
        float biasv = bias[col];
        float mean = rawstats[col] / (float)N;
        float var  = rawstats[128 + col] / (float)N - mean * mean;
        float scv = gg[col] * rsqrtf(var + 1e-5f);
        float shv = bb[col] - mean * scv;
        #pragma unroll
        for (int s = 0; s < 2; ++s) {
            #pragma unroll
            for (int r = 0; r < 4; ++r) {
                int grow = row0 + s * 16 + lq * 4 + r;
                if (grow >= N) continue;
                size_t o = (size_t)grow * M + col;
                float v = acc[s][ct][r] + biasv + fmaf(bf2f((short)extb[o]), scv, shv);
                outb[o] = f2bf(v);
            }
        }
    }
}

// ---------------------------------------------------------------------------
// Merged: weight conversion + src fp32->bf16 + edge degree count.
// ---------------------------------------------------------------------------
__global__ __launch_bounds__(256)
void convert_deg_kernel(const float* __restrict__ qw, const float* __restrict__ qb,
                        const float* __restrict__ kw, const float* __restrict__ vw,
                        const float* __restrict__ ow, const float* __restrict__ w1,
                        const float* __restrict__ w2,
                        ushort* __restrict__ wqkv, ushort* __restrict__ wout,
                        ushort* __restrict__ w1b, ushort* __restrict__ w2b,
                        float* __restrict__ bqkv,
                        const float* __restrict__ src, ushort* __restrict__ srcbf,
                        int nd8,
                        const int* __restrict__ ei, long long E0,
                        int* __restrict__ deg)
{
    long long i = (long long)blockIdx.x * 256 + threadIdx.x;
    if (i < E0) atomicAdd(&deg[ei[E0 + i]], 1);
    if (i < nd8) {
        const float4* sp = (const float4*)(src + i * 8);
        float4 f0 = sp[0], f1 = sp[1];
        ushort u[8];
        u[0]=f2bf(f0.x); u[1]=f2bf(f0.y); u[2]=f2bf(f0.z); u[3]=f2bf(f0.w);
        u[4]=f2bf(f1.x); u[5]=f2bf(f1.y); u[6]=f2bf(f1.z); u[7]=f2bf(f1.w);
        *(uint4*)(srcbf + i * 8) = *(uint4*)u;
    }
    if (i < 49152) {
        int row = (int)i >> 7;
        float v;
        if (row < 128)      v = 0.25f * qw[i];
        else if (row < 256) v = kw[i - 16384];
        else                v = vw[i - 32768];
        wqkv[i] = f2bf(v);
        return;
    }
    long long j = i - 49152;
    if (j < 16384) { wout[j] = f2bf(ow[j]); return; }
    j -= 16384;
    if (j < 65536) { w1b[j] = f2bf(w1[j]); return; }
    j -= 65536;
    if (j < 65536) { w2b[j] = f2bf(w2[j]); return; }
    j -= 65536;
    if (j < 384) bqkv[j] = (j < 128) ? 0.25f * qb[j] : 0.f;
}

// ---------------------------------------------------------------------------
// Fold BN1 into lin1 weights: w1f[f][k] = bf16(w1[f][k]*sc[k]);
// bias1f[f] = lin1_b[f] + sum_k sh[k]*w1[f][k].  One wave per f row.
// ---------------------------------------------------------------------------
__global__ __launch_bounds__(256)
void w1fold_kernel(const ushort* __restrict__ w1b, const float* __restrict__ lb1,
                   const float* __restrict__ rawstats,
                   const float* __restrict__ g1, const float* __restrict__ b1,
                   ushort* __restrict__ w1f, float* __restrict__ bias1f, int N)
{
    int f = blockIdx.x * 4 + (threadIdx.x >> 6);   // 512 rows, grid 128
    int lane = threadIdx.x & 63;
    int k0 = lane * 2;
    float m0 = rawstats[k0] / (float)N;
    float v0 = rawstats[128 + k0] / (float)N - m0 * m0;
    float sc0 = g1[k0] * rsqrtf(v0 + 1e-5f);
    float sh0 = b1[k0] - m0 * sc0;
    float m1 = rawstats[k0 + 1] / (float)N;
    float v1 = rawstats[128 + k0 + 1] / (float)N - m1 * m1;
    float sc1 = g1[k0 + 1] * rsqrtf(v1 + 1e-5f);
    float sh1 = b1[k0 + 1] - m1 * sc1;

    uint wp = *(const uint*)(w1b + (size_t)f * 128 + k0);
    float w0 = bflo(wp), w1v = bfhi(wp);
    uint o = (uint)f2bf(w0 * sc0) | ((uint)f2bf(w1v * sc1) << 16);
    *(uint*)(w1f + (size_t)f * 128 + k0) = o;

    float part = w0 * sh0 + w1v * sh1;
    #pragma unroll
    for (int m = 1; m < 64; m <<= 1) part += __shfl_xor(part, m, 64);
    if (lane == 0) bias1f[f] = lb1[f] + part;
}

// ---------------------------------------------------------------------------
// CSR build scans + scatter.
// ---------------------------------------------------------------------------
__global__ __launch_bounds__(256)
void scan_block_sum(const int* __restrict__ deg, int n, int* __restrict__ bsum)
{
    __shared__ int sh[256];
    int i = blockIdx.x * 256 + threadIdx.x;
    sh[threadIdx.x] = (i < n) ? deg[i] : 0;
    __syncthreads();
    for (int ofs = 128; ofs > 0; ofs >>= 1) {
        if (threadIdx.x < ofs) sh[threadIdx.x] += sh[threadIdx.x + ofs];
        __syncthreads();
    }
    if (threadIdx.x == 0) bsum[blockIdx.x] = sh[0];
}

__global__ __launch_bounds__(256)
void scan_final(const int* __restrict__ deg, int n, const int* __restrict__ bsum,
                int nb, int* __restrict__ rowptr)
{
    __shared__ int sb[256];
    __shared__ int sh[256];
    int t = threadIdx.x;
    sb[t] = (t < nb) ? bsum[t] : 0;
    __syncthreads();
    for (int ofs = 1; ofs < 256; ofs <<= 1) {
        int v = (t >= ofs) ? sb[t - ofs] : 0;
        __syncthreads();
        sb[t] += v;
        __syncthreads();
    }
    int boff = (blockIdx.x == 0) ? 0 : sb[blockIdx.x - 1];

    int i = blockIdx.x * 256 + t;
    int v = (i < n) ? deg[i] : 0;
    sh[t] = v;
    __syncthreads();
    for (int ofs = 1; ofs < 256; ofs <<= 1) {
        int u = (t >= ofs) ? sh[t - ofs] : 0;
        __syncthreads();
        sh[t] += u;
        __syncthreads();
    }
    if (i < n) rowptr[i] = boff + sh[t] - v;
    if (i == n - 1) rowptr[n] = boff + sh[t];
}

__global__ __launch_bounds__(256)
void scatter_kernel(const int* __restrict__ ei, long long E0,
                    const int* __restrict__ rowptr, int* __restrict__ cnt,
                    int* __restrict__ col)
{
    long long e = (long long)blockIdx.x * 256 + threadIdx.x;
    if (e >= E0) return;
    int s = ei[e], d = ei[E0 + e];
    int pos = rowptr[d] + atomicAdd(&cnt[d], 1);
    col[pos] = s;
}

// ---------------------------------------------------------------------------
// Fused gather attention, WAVE-PER-NODE (R7-proven).
// ---------------------------------------------------------------------------
__global__ __launch_bounds__(256)
void gat_agg_kernel(const int* __restrict__ rowptr, const int* __restrict__ col,
                    const ushort* __restrict__ qkv, ushort* __restrict__ agg, int N)
{
    int node = blockIdx.x * 4 + (threadIdx.x >> 6);
    if (node >= N) return;
    int lane = threadIdx.x & 63;
    int es = lane >> 3, h = lane & 7;
    const uint4* Q = (const uint4*)qkv;

    const uint4* qp = Q + (size_t)node * 48 + h * 2;
    uint4 qa = qp[0], qb = qp[1];
    float qf[16];
    qf[0]=bflo(qa.x); qf[1]=bfhi(qa.x); qf[2]=bflo(qa.y); qf[3]=bfhi(qa.y);
    qf[4]=bflo(qa.z); qf[5]=bfhi(qa.z); qf[6]=bflo(qa.w); qf[7]=bfhi(qa.w);
    qf[8]=bflo(qb.x); qf[9]=bfhi(qb.x); qf[10]=bflo(qb.y); qf[11]=bfhi(qb.y);
    qf[12]=bflo(qb.z); qf[13]=bfhi(qb.z); qf[14]=bflo(qb.w); qf[15]=bfhi(qb.w);

    float num[16];
    #pragma unroll
    for (int i = 0; i < 16; i++) num[i] = 0.f;
    float den = 0.f;

    int beg = rowptr[node];
    int total = rowptr[node + 1] - beg + 1;
    for (int idx = es; idx < total; idx += 8) {
        int s = (idx == 0) ? node : col[beg + idx - 1];
        const uint4* rp = Q + (size_t)s * 48 + h * 2;
        uint4 ka = rp[16], kb = rp[17], va = rp[32], vb = rp[33];
        float ev = __expf(dot16(qf, ka, kb));
        den += ev;
        acc16(num, ev, va, vb);
    }

    #pragma unroll
    for (int m = 8; m < 64; m <<= 1) {
        den += __shfl_xor(den, m, 64);
        #pragma unroll
        for (int i = 0; i < 16; i++) num[i] += __shfl_xor(num[i], m, 64);
    }

    if (es == 0) {
        float inv = 1.f / (den + 1e-16f);
        uint4 o0, o1;
        o0.x = (uint)f2bf(num[0]*inv)  | ((uint)f2bf(num[1]*inv)  << 16);
        o0.y = (uint)f2bf(num[2]*inv)  | ((uint)f2bf(num[3]*inv)  << 16);
        o0.z = (uint)f2bf(num[4]*inv)  | ((uint)f2bf(num[5]*inv)  << 16);
        o0.w = (uint)f2bf(num[6]*inv)  | ((uint)f2bf(num[7]*inv)  << 16);
        o1.x = (uint)f2bf(num[8]*inv)  | ((uint)f2bf(num[9]*inv)  << 16);
        o1.y = (uint)f2bf(num[10]*inv) | ((uint)f2bf(num[11]*inv) << 16);
        o1.z = (uint)f2bf(num[12]*inv) | ((uint)f2bf(num[13]*inv) << 16);
        o1.w = (uint)f2bf(num[14]*inv) | ((uint)f2bf(num[15]*inv) << 16);
        uint4* op = (uint4*)(agg + (size_t)node * 128 + h * 16);
        op[0] = o0; op[1] = o1;
    }
}

// ---------------------------------------------------------------------------
// BatchNorm raw stats over bf16 [N x 128].
// ---------------------------------------------------------------------------
__global__ __launch_bounds__(256)
void bn_stats_bf16_kernel(const ushort* __restrict__ y, int N, float* __restrict__ stats)
{
    int jp = threadIdx.x & 63;
    int q4 = threadIdx.x >> 6;
    int r = blockIdx.x * 256 + q4;
    int rend = min(N, (int)(blockIdx.x + 1) * 256);
    float s0 = 0.f, qq0 = 0.f, s1 = 0.f, qq1 = 0.f;
    const uint* yp = (const uint*)y;
    for (; r < rend; r += 4) {
        uint u = yp[(size_t)r * 64 + jp];
        float a = bflo(u), b = bfhi(u);
        s0 += a; qq0 += a * a; s1 += b; qq1 += b * b;
    }
    __shared__ float sh[4][64][4];
    sh[q4][jp][0] = s0; sh[q4][jp][1] = qq0; sh[q4][jp][2] = s1; sh[q4][jp][3] = qq1;
    __syncthreads();
    if (threadIdx.x < 128) {
        int p = threadIdx.x >> 1;
        int w = threadIdx.x & 1;
        float ss = 0.f, sq = 0.f;
        #pragma unroll
        for (int i = 0; i < 4; i++) { ss += sh[i][p][w * 2]; sq += sh[i][p][w * 2 + 1]; }
        unsafeAtomicAdd(&stats[2 * p + w], ss);
        unsafeAtomicAdd(&stats[128 + 2 * p + w], sq);
    }
}

// final BN apply (finalize folded): bf16 in -> fp32 out
__global__ __launch_bounds__(256)
void bn_apply_out_kernel(const ushort* __restrict__ y, const float* __restrict__ rawstats,
                         const float* __restrict__ g, const float* __restrict__ b,
                         float* __restrict__ out, int total4, int N)
{
    __shared__ float scs[128], shs[128];
    if (threadIdx.x < 128) {
        int j = threadIdx.x;
        float mean = rawstats[j] / (float)N;
        float var  = rawstats[128 + j] / (float)N - mean * mean;
        float sc = g[j] * rsqrtf(var + 1e-5f);
        scs[j] = sc;
        shs[j] = b[j] - mean * sc;
    }
    __syncthreads();
    int i = blockIdx.x * 256 + threadIdx.x;
    if (i >= total4) return;
    uint2 u = reinterpret_cast<const uint2*>(y)[i];
    int j = (i * 4) & (D - 1);
    float4 v;
    v.x = bflo(u.x) * scs[j + 0] + shs[j + 0];
    v.y = bfhi(u.x) * scs[j + 1] + shs[j + 1];
    v.z = bflo(u.y) * scs[j + 2] + shs[j + 2];
    v.w = bfhi(u.y) * scs[j + 3] + shs[j + 3];
    reinterpret_cast<float4*>(out)[i] = v;
}

// ---------------------------------------------------------------------------
extern "C" void kernel_launch(void* const* d_in, const int* in_sizes, int n_in,
                              void* d_out, int out_size, void* d_ws, size_t ws_size,
                              hipStream_t stream)
{
    const float* src    = (const float*)d_in[0];
    const int*   ei     = (const int*)  d_in[1];
    const float* q_w    = (const float*)d_in[2];
    const float* q_b    = (const float*)d_in[3];
    const float* k_w    = (const float*)d_in[4];
    const float* v_w    = (const float*)d_in[5];
    const float* out_w  = (const float*)d_in[6];
    const float* out_b  = (const float*)d_in[7];
    const float* g1     = (const float*)d_in[8];
    const float* b1     = (const float*)d_in[9];
    const float* lin1_w = (const float*)d_in[10];
    const float* lin1_b = (const float*)d_in[11];
    const float* lin2_w = (const float*)d_in[12];
    const float* lin2_b = (const float*)d_in[13];
    const float* g2     = (const float*)d_in[14];
    const float* b2     = (const float*)d_in[15];

    const int N        = in_sizes[0] / D;        // 50000
    const long long E0 = in_sizes[1] / 2;        // 800000

    // ---- workspace layout (float units) ----
    float* ws = (float*)d_ws;
    size_t off = 0;
    ushort* qkv   = (ushort*)(ws + off); off += (size_t)N * 192;   // N*384 bf16
    ushort* agg   = (ushort*)(ws + off); off += (size_t)N * 64;
    ushort* srcbf = (ushort*)(ws + off); off += (size_t)N * 64;
    ushort* y1b   = (ushort*)(ws + off); off += (size_t)N * 64;
    ushort* hid   = (ushort*)(ws + off); off += (size_t)N * 256;   // N*512 bf16
    ushort* y2b   = (ushort*)(ws + off); off += (size_t)N * 64;
    ushort* wqkv  = (ushort*)(ws + off); off += 24576;             // 384*128
    ushort* woutb = (ushort*)(ws + off); off += 8192;              // 128*128
    ushort* w1b   = (ushort*)(ws + off); off += 32768;             // 512*128
    ushort* w1f   = (ushort*)(ws + off); off += 32768;             // folded
    ushort* w2b   = (ushort*)(ws + off); off += 32768;             // 128*512
    float*  bqkv  = ws + off;            off += 384;
    float*  bias1f= ws + off;            off += 512;
    size_t zero_start = off;
    int* deg    = (int*)(ws + off); off += N;
    int* cnt    = (int*)(ws + off); off += N;
    float* stats1 = ws + off; off += 512;
    float* stats2 = ws + off; off += 512;
    size_t zero_cnt = off - zero_start;
    int* rowptr = (int*)(ws + off); off += N + 1;
    int* bsum   = (int*)(ws + off); off += 256;
    int* col    = (int*)(ws + off); off += E0;

    hipMemsetAsync(ws + zero_start, 0, zero_cnt * sizeof(float), stream);

    dim3 blk(256);

    // ---- merged weight conversion + src->bf16 + degree count ----
    dim3 gE0((unsigned)((E0 + 255) / 256));
    hipLaunchKernelGGL(convert_deg_kernel, gE0, blk, 0, stream,
                       q_w, q_b, k_w, v_w, out_w, lin1_w, lin2_w,
                       wqkv, woutb, w1b, w2b, bqkv,
                       src, srcbf, N * 16, ei, E0, deg);

    // ---- CSR scans + scatter ----
    int nb = (N + 255) / 256;
    hipLaunchKernelGGL(scan_block_sum, dim3(nb), blk, 0, stream, deg, N, bsum);
    hipLaunchKernelGGL(scan_final, dim3(nb), blk, 0, stream, deg, N, bsum, nb, rowptr);
    hipLaunchKernelGGL(scatter_kernel, gE0, blk, 0, stream, ei, E0, rowptr, cnt, col);

    const int gx = 1024;   // grid-stride row blocks (4 blocks/CU resident)

    // ---- QKV projection (B-stationary, bf16 A), M=384 ----
    hipLaunchKernelGGL((gemm_v4_kernel<0, 384>), dim3(gx, 3), blk, 0, stream,
                       srcbf, wqkv, bqkv, nullptr, qkv, N);

    // ---- fused softmax + aggregation (wave per node) ----
    hipLaunchKernelGGL(gat_agg_kernel, dim3((N + 3) / 4), blk, 0, stream,
                       rowptr, col, qkv, agg, N);

    // ---- out-projection + bias + fp32 src residual -> y1b ----
    hipLaunchKernelGGL((gemm_v4_kernel<3, 128>), dim3(gx, 1), blk, 0, stream,
                       agg, woutb, out_b, src, y1b, N);

    // ---- BN1 raw stats ----
    dim3 gS((N + 255) / 256);
    hipLaunchKernelGGL(bn_stats_bf16_kernel, gS, blk, 0, stream, y1b, N, stats1);

    // ---- fold BN1 into lin1 weights ----
    hipLaunchKernelGGL(w1fold_kernel, dim3(128), blk, 0, stream,
                       w1b, lin1_b, stats1, g1, b1, w1f, bias1f, N);

    // ---- lin1 (B-stationary, folded BN) + leaky -> hid, M=512 ----
    hipLaunchKernelGGL((gemm_v4_kernel<2, 512>), dim3(gx, 4), blk, 0, stream,
                       y1b, w1f, bias1f, nullptr, hid, N);

    // ---- lin2 + bias + BN1(y1b) residual -> y2b (K=512, v2 path) ----
    hipLaunchKernelGGL((gemm_v2_kernel<512, 32>), dim3((N + 31) / 32), blk, 0, stream,
                       hid, w2b, lin2_b, y1b, stats1, g1, b1, y2b, N);

    // ---- BN2 raw stats + apply -> d_out fp32 ----
    hipLaunchKernelGGL(bn_stats_bf16_kernel, gS, blk, 0, stream, y2b, N, stats2);
    int total4 = N * D / 4;
    hipLaunchKernelGGL(bn_apply_out_kernel, dim3((total4 + 255) / 256), blk, 0, stream,
                       y2b, stats2, g2, b2, (float*)d_out, total4, N);
}